// Round 1
// baseline (288.367 us; speedup 1.0000x reference)
//
#include <hip/hip_runtime.h>

// ConvDeIndexer via densify + MFMA.
//   y[b, 32m+ocg, 4w+i, 4h+j] = sum_c X[c,h] * W[64m+c][ocg][i][j]   (per b,m,w)
// Per (b,m,w): D[p,h] = sum_c Wt[p,c] * X[c,h],  p = ocg*16+i*4+j (M=512),
// h (N=64), c (K=64).  mfma_f32_16x16x32_bf16, A=Wt (m=p), B=X (n=h).
// C-layout: n=lane&15 (h), m=quad*4+reg -> quad=i, reg=j: each lane's 4 accs are
// one contiguous output float4 at (oc, oy=4w+i, ox=4h..4h+3). Direct NT stores.
//
// R1 restructure: 4 w-columns per block (grid 2048 -> 512).
//  - sA (36 KB) staged once per chunk, reused for 4 w (L2 weight traffic halved).
//  - densify fully parallel: 256 thr = 4w x 64h, each thread loads its own 8
//    (ind,val) pairs straight from global (coalesced over h) and writes them in
//    scatter order (pos k0..3 then neg k0..3) -> later-write-wins preserved.
//  - A fragments hoisted out of the w loop; 4x store work per barrier region.
// LDS 72 KB -> 2 blocks/CU, all 512 blocks co-resident.

typedef float f32x4  __attribute__((ext_vector_type(4)));
typedef short bf16x8 __attribute__((ext_vector_type(8)));

__device__ __forceinline__ unsigned short f32_to_bf16_rne(float f) {
    unsigned int u = __float_as_uint(f);
    return (unsigned short)((u + 0x7FFFu + ((u >> 16) & 1u)) >> 16);
}

// ---- Kernel 1: weight f32 [cin=512][p=512] -> bf16 ws[m=8][p=512][c=64] ----
__global__ __launch_bounds__(256) void wt_transpose_kernel(
    const float* __restrict__ weight, unsigned short* __restrict__ ws)
{
    __shared__ unsigned short stile[64 * 72];   // [p-local][c], stride 72
    const int m    = blockIdx.x >> 3;
    const int pblk = blockIdx.x & 7;
    const int t    = threadIdx.x;
    const int p    = t & 63;
    const int chi  = t >> 6;                    // 0..3
    #pragma unroll
    for (int r = 0; r < 16; ++r) {
        const int c = chi * 16 + r;
        const float v = weight[(size_t)(64 * m + c) * 512 + pblk * 64 + p]; // coalesced over p
        stile[p * 72 + c] = f32_to_bf16_rne(v);
    }
    __syncthreads();
    uint4* dst4 = (uint4*)(ws + (size_t)(m * 512 + pblk * 64) * 64);
    #pragma unroll
    for (int pass = 0; pass < 2; ++pass) {
        const int g = pass * 256 + t;           // granule 0..511 (64 rows x 8)
        const uint4 v = *(const uint4*)(stile + (g >> 3) * 72 + (g & 7) * 8);
        dst4[g] = v;                            // contiguous coalesced
    }
}

// ---- Kernel 2: main. One block per (b, m, w-group-of-4). ----
__global__ __launch_bounds__(256) void convdeidx_mfma_kernel(
    const int* __restrict__ ind_pos, const int* __restrict__ ind_neg,
    const float* __restrict__ val_pos, const float* __restrict__ val_neg,
    const unsigned short* __restrict__ ws, float* __restrict__ out)
{
    __shared__ unsigned short sA[256 * 72];       // 36 KB: weight chunk, 256 p rows
    __shared__ unsigned short sX[4 * 64 * 72];    // 36 KB: [wl][h][c], stride 72

    const int bi  = blockIdx.x;                   // = (b*8 + m)*16 + wg
    const int wg  = bi & 15;
    const int m   = (bi >> 4) & 7;
    const int b   = bi >> 7;
    const int w0  = wg * 4;
    const int tid = threadIdx.x;
    const int wid = tid >> 6, lane = tid & 63;
    const int q   = lane >> 4, ln = lane & 15;    // quad, lane-in-16

    // ---- load this thread's 8 (ind,val) pairs: thread = (wl, h) ----
    const int wl = tid >> 6;                      // w-local 0..3 (== wave id)
    const int h  = tid & 63;
    int   ipos[4], ineg[4];
    float vpos[4], vneg[4];
    #pragma unroll
    for (int k = 0; k < 4; ++k) {
        const size_t idx = ((((size_t)b * 4 + k) * 8 + m) * 64 + (w0 + wl)) * 64 + h;
        ipos[k] = ind_pos[idx]; vpos[k] = val_pos[idx];   // coalesced over h
        ineg[k] = ind_neg[idx]; vneg[k] = val_neg[idx];
    }

    // ---- zero sX: 2304 uint4, 9 per thread ----
    {
        uint4* x4 = (uint4*)sX;
        const uint4 z = make_uint4(0u, 0u, 0u, 0u);
        #pragma unroll
        for (int r = 0; r < 9; ++r) x4[r * 256 + tid] = z;
    }

    // ---- stage sA chunk 0: ws[m][0..255][c] -> rows of stride 72 ----
    const uint4* wsrc4 = (const uint4*)(ws + (size_t)m * 512 * 64); // granule = 8 shorts
    #pragma unroll
    for (int r = 0; r < 8; ++r) {
        const int g = r * 256 + tid;              // 0..2047
        const uint4 v = wsrc4[g];
        *(uint4*)(sA + (g >> 3) * 72 + (g & 7) * 8) = v;
    }
    __syncthreads();                              // zeroing + sA writes visible

    // ---- densify: thread (wl,h) writes its 8 pairs in order -> last write wins
    {
        unsigned short* xrow = sX + (wl * 64 + h) * 72;
        #pragma unroll
        for (int k = 0; k < 4; ++k) xrow[ipos[k]] = f32_to_bf16_rne(vpos[k]);
        #pragma unroll
        for (int k = 0; k < 4; ++k) xrow[ineg[k]] = f32_to_bf16_rne(vneg[k]);
    }
    __syncthreads();

    f32x4* outv = (f32x4*)out;

    #pragma unroll
    for (int chunk = 0; chunk < 2; ++chunk) {
        if (chunk == 1) {
            __syncthreads();                      // chunk0 sA frag reads done
            #pragma unroll
            for (int r = 0; r < 8; ++r) {
                const int g = r * 256 + tid;
                const uint4 v = wsrc4[2048 + g];
                *(uint4*)(sA + (g >> 3) * 72 + (g & 7) * 8) = v;
            }
            __syncthreads();
        }

        // A fragments fixed across the w loop: row = wid*64 + mt*16 + ln
        bf16x8 afr[2][4];
        #pragma unroll
        for (int kt = 0; kt < 2; ++kt)
            #pragma unroll
            for (int mt = 0; mt < 4; ++mt)
                afr[kt][mt] = *(const bf16x8*)(sA + (wid * 64 + mt * 16 + ln) * 72 + (kt * 4 + q) * 8);

        const int ocg0 = chunk * 16 + wid * 4;

        #pragma unroll
        for (int ww = 0; ww < 4; ++ww) {
            bf16x8 bfr[2][4];
            #pragma unroll
            for (int kt = 0; kt < 2; ++kt)
                #pragma unroll
                for (int nt = 0; nt < 4; ++nt)    // B[k=c][n=h]: stored [h][c]
                    bfr[kt][nt] = *(const bf16x8*)(sX + (ww * 64 + nt * 16 + ln) * 72 + (kt * 4 + q) * 8);

            f32x4 acc[4][4];
            #pragma unroll
            for (int mt = 0; mt < 4; ++mt)
                #pragma unroll
                for (int nt = 0; nt < 4; ++nt)
                    acc[mt][nt] = (f32x4){0.f, 0.f, 0.f, 0.f};

            #pragma unroll
            for (int kt = 0; kt < 2; ++kt)
                #pragma unroll
                for (int mt = 0; mt < 4; ++mt)
                    #pragma unroll
                    for (int nt = 0; nt < 4; ++nt)
                        acc[mt][nt] = __builtin_amdgcn_mfma_f32_16x16x32_bf16(
                            afr[kt][mt], bfr[kt][nt], acc[mt][nt], 0, 0, 0);

            // stores: p = chunk*256 + wid*64 + mt*16 + (q*4+reg)
            //   -> ocg = chunk*16 + wid*4 + mt, i = q, j = reg; h = nt*16 + ln
            #pragma unroll
            for (int mt = 0; mt < 4; ++mt) {
                const size_t rowbase =
                    ((size_t)(b * 256 + m * 32 + ocg0 + mt) * 256 + ((w0 + ww) * 4 + q)) * 64;
                #pragma unroll
                for (int nt = 0; nt < 4; ++nt)
                    __builtin_nontemporal_store(acc[mt][nt], outv + rowbase + nt * 16 + ln);
            }
        }
    }
}

extern "C" void kernel_launch(void* const* d_in, const int* in_sizes, int n_in,
                              void* d_out, int out_size, void* d_ws, size_t ws_size,
                              hipStream_t stream) {
    const int*   ind_pos = (const int*)  d_in[0];
    const int*   ind_neg = (const int*)  d_in[1];
    const float* val_pos = (const float*)d_in[2];
    const float* val_neg = (const float*)d_in[3];
    const float* weight  = (const float*)d_in[4];
    float*       y       = (float*)d_out;
    unsigned short* ws   = (unsigned short*)d_ws;   // needs 512 KB

    hipLaunchKernelGGL(wt_transpose_kernel, dim3(64), dim3(256), 0, stream, weight, ws);
    hipLaunchKernelGGL(convdeidx_mfma_kernel, dim3(512), dim3(256), 0, stream,
                       ind_pos, ind_neg, val_pos, val_neg, ws, y);
}

// Round 2
// 281.266 us; speedup vs baseline: 1.0252x; 1.0252x over previous
//
#include <hip/hip_runtime.h>

// ConvDeIndexer via densify + MFMA.
//   y[b, 32m+ocg, 4w+i, 4h+j] = sum_c X[c,h] * W[64m+c][ocg][i][j]   (per b,m,w)
// Per (b,m,w): D[p,h] = sum_c Wt[p,c] * X[c,h],  p = ocg*16+i*4+j (M=512),
// h (N=64), c (K=64).  mfma_f32_16x16x32_bf16, A=Wt (m=p), B=X (n=h).
// C-layout: n=lane&15 (h), m=quad*4+reg -> quad=i, reg=j: each lane's 4 accs are
// one contiguous output float4 at (oc, oy=4w+i, ox=4h..4h+3). Direct NT stores.
//
// R2 restructure: NO weight LDS staging. ws[m][p][c] is fragment-contiguous, so
// A-fragments are direct global_load_dwordx4 from the L2-resident 512 KB ws.
// Main loop is barrier-free (only 2 barriers/block, both before it). w-group=2,
// grid 1024, sX 18 KB, __launch_bounds__(256,4) -> <=128 VGPR -> 4 blocks/CU
// (16 waves/CU), 2x R1 occupancy, to cover fragload->MFMA->store chains.

typedef float f32x4  __attribute__((ext_vector_type(4)));
typedef short bf16x8 __attribute__((ext_vector_type(8)));

__device__ __forceinline__ unsigned short f32_to_bf16_rne(float f) {
    unsigned int u = __float_as_uint(f);
    return (unsigned short)((u + 0x7FFFu + ((u >> 16) & 1u)) >> 16);
}

// ---- Kernel 1: weight f32 [cin=512][p=512] -> bf16 ws[m=8][p=512][c=64] ----
__global__ __launch_bounds__(256) void wt_transpose_kernel(
    const float* __restrict__ weight, unsigned short* __restrict__ ws)
{
    __shared__ unsigned short stile[64 * 72];   // [p-local][c], stride 72
    const int m    = blockIdx.x >> 3;
    const int pblk = blockIdx.x & 7;
    const int t    = threadIdx.x;
    const int p    = t & 63;
    const int chi  = t >> 6;                    // 0..3
    #pragma unroll
    for (int r = 0; r < 16; ++r) {
        const int c = chi * 16 + r;
        const float v = weight[(size_t)(64 * m + c) * 512 + pblk * 64 + p]; // coalesced over p
        stile[p * 72 + c] = f32_to_bf16_rne(v);
    }
    __syncthreads();
    uint4* dst4 = (uint4*)(ws + (size_t)(m * 512 + pblk * 64) * 64);
    #pragma unroll
    for (int pass = 0; pass < 2; ++pass) {
        const int g = pass * 256 + t;           // granule 0..511 (64 rows x 8)
        const uint4 v = *(const uint4*)(stile + (g >> 3) * 72 + (g & 7) * 8);
        dst4[g] = v;                            // contiguous coalesced
    }
}

// ---- Kernel 2: main. One block per (b, m, w-pair). ----
__global__ __launch_bounds__(256, 4) void convdeidx_mfma_kernel(
    const int* __restrict__ ind_pos, const int* __restrict__ ind_neg,
    const float* __restrict__ val_pos, const float* __restrict__ val_neg,
    const unsigned short* __restrict__ ws, float* __restrict__ out)
{
    __shared__ unsigned short sX[2 * 64 * 72];    // 18 KB: [wl][h][c], stride 72

    const int bi  = blockIdx.x;                   // = ((b*8 + m)*32 + wg)
    const int wg  = bi & 31;
    const int m   = (bi >> 5) & 7;
    const int b   = bi >> 8;
    const int w0  = wg * 2;
    const int tid = threadIdx.x;
    const int wid = tid >> 6, lane = tid & 63;
    const int q   = lane >> 4, ln = lane & 15;    // quad, lane-in-16

    // ---- load pairs: threads 0..127 = (wl, h); one thread owns one X row ----
    int   ipos[4], ineg[4];
    float vpos[4], vneg[4];
    const int wl = (tid >> 6) & 1;
    const int h  = tid & 63;
    if (tid < 128) {
        #pragma unroll
        for (int k = 0; k < 4; ++k) {
            const size_t idx = ((((size_t)b * 4 + k) * 8 + m) * 64 + (w0 + wl)) * 64 + h;
            ipos[k] = ind_pos[idx]; vpos[k] = val_pos[idx];   // coalesced over h
            ineg[k] = ind_neg[idx]; vneg[k] = val_neg[idx];
        }
    }

    // ---- zero sX: 1152 uint4 ----
    {
        uint4* x4 = (uint4*)sX;
        const uint4 z = make_uint4(0u, 0u, 0u, 0u);
        #pragma unroll
        for (int r = 0; r < 4; ++r) x4[r * 256 + tid] = z;
        if (tid < 128) x4[1024 + tid] = z;
    }
    __syncthreads();

    // ---- densify: thread (wl,h) writes its 8 pairs in order -> last write wins
    if (tid < 128) {
        unsigned short* xrow = sX + (wl * 64 + h) * 72;
        #pragma unroll
        for (int k = 0; k < 4; ++k) xrow[ipos[k]] = f32_to_bf16_rne(vpos[k]);
        #pragma unroll
        for (int k = 0; k < 4; ++k) xrow[ineg[k]] = f32_to_bf16_rne(vneg[k]);
    }
    __syncthreads();

    // ---- main loop: barrier-free {A-frag from L2, B-frag from LDS, MFMA, NT store}
    const unsigned short* wsm = ws + (size_t)m * 512 * 64;
    f32x4* outv = (f32x4*)out;

    #pragma unroll
    for (int chunk = 0; chunk < 2; ++chunk) {
        // A fragments direct from global (L2-resident), fragment-contiguous:
        // row p = chunk*256 + wid*64 + mt*16 + ln, shorts [(kt*4+q)*8 ..+8)
        bf16x8 afr[2][4];
        #pragma unroll
        for (int kt = 0; kt < 2; ++kt)
            #pragma unroll
            for (int mt = 0; mt < 4; ++mt)
                afr[kt][mt] = *(const bf16x8*)(
                    wsm + ((size_t)(chunk * 256 + wid * 64 + mt * 16 + ln) << 6) + (kt * 4 + q) * 8);

        const int ocg0 = chunk * 16 + wid * 4;

        #pragma unroll
        for (int ww = 0; ww < 2; ++ww) {
            #pragma unroll
            for (int nh = 0; nh < 2; ++nh) {      // n-half: nt = nh*2 + nt2
                bf16x8 bfr[2][2];
                #pragma unroll
                for (int kt = 0; kt < 2; ++kt)
                    #pragma unroll
                    for (int nt2 = 0; nt2 < 2; ++nt2)
                        bfr[kt][nt2] = *(const bf16x8*)(
                            sX + (ww * 64 + (nh * 2 + nt2) * 16 + ln) * 72 + (kt * 4 + q) * 8);

                f32x4 acc[4][2];
                #pragma unroll
                for (int mt = 0; mt < 4; ++mt)
                    #pragma unroll
                    for (int nt2 = 0; nt2 < 2; ++nt2)
                        acc[mt][nt2] = (f32x4){0.f, 0.f, 0.f, 0.f};

                #pragma unroll
                for (int kt = 0; kt < 2; ++kt)
                    #pragma unroll
                    for (int mt = 0; mt < 4; ++mt)
                        #pragma unroll
                        for (int nt2 = 0; nt2 < 2; ++nt2)
                            acc[mt][nt2] = __builtin_amdgcn_mfma_f32_16x16x32_bf16(
                                afr[kt][mt], bfr[kt][nt2], acc[mt][nt2], 0, 0, 0);

                // stores: oc = chunk*16 + wid*4 + mt, oy = (w0+ww)*4 + q,
                //         col float4 = (nh*2+nt2)*16 + ln
                #pragma unroll
                for (int mt = 0; mt < 4; ++mt) {
                    const size_t rowbase =
                        ((size_t)(b * 256 + m * 32 + ocg0 + mt) * 256 + ((w0 + ww) * 4 + q)) * 64;
                    #pragma unroll
                    for (int nt2 = 0; nt2 < 2; ++nt2)
                        __builtin_nontemporal_store(
                            acc[mt][nt2], outv + rowbase + (nh * 2 + nt2) * 16 + ln);
                }
            }
        }
    }
}

extern "C" void kernel_launch(void* const* d_in, const int* in_sizes, int n_in,
                              void* d_out, int out_size, void* d_ws, size_t ws_size,
                              hipStream_t stream) {
    const int*   ind_pos = (const int*)  d_in[0];
    const int*   ind_neg = (const int*)  d_in[1];
    const float* val_pos = (const float*)d_in[2];
    const float* val_neg = (const float*)d_in[3];
    const float* weight  = (const float*)d_in[4];
    float*       y       = (float*)d_out;
    unsigned short* ws   = (unsigned short*)d_ws;   // needs 512 KB

    hipLaunchKernelGGL(wt_transpose_kernel, dim3(64), dim3(256), 0, stream, weight, ws);
    hipLaunchKernelGGL(convdeidx_mfma_kernel, dim3(1024), dim3(256), 0, stream,
                       ind_pos, ind_neg, val_pos, val_neg, ws, y);
}

// Round 3
// 279.438 us; speedup vs baseline: 1.0320x; 1.0065x over previous
//
#include <hip/hip_runtime.h>

// ConvDeIndexer via densify + MFMA.
//   y[b, 32m+ocg, 4w+i, 4h+j] = sum_c X[c,h] * W[64m+c][ocg][i][j]   (per b,m,w)
// Per (b,m,w): D[p,h] = sum_c Wt[p,c] * X[c,h],  p = ocg*16+i*4+j (M=512),
// h (N=64), c (K=64).  mfma_f32_16x16x32_bf16, A=Wt (m=p), B=X (n=h).
// C-layout: n=lane&15 (h), m=quad*4+reg -> quad=i, reg=j: each lane's 4 accs are
// one contiguous output float4 at (oc, oy=4w+i, ox=4h..4h+3). Direct stores.
//
// R3 A/B: identical to R2 except __builtin_nontemporal_store -> plain stores.
// R0/R1/R2 all used NT stores and all landed 281-288 us despite wildly
// different schedules -> the untested invariant is the NT write path itself.
// If gfx950's nt (L2-bypass) caps streaming-store BW, plain stores fix it.

typedef float f32x4  __attribute__((ext_vector_type(4)));
typedef short bf16x8 __attribute__((ext_vector_type(8)));

__device__ __forceinline__ unsigned short f32_to_bf16_rne(float f) {
    unsigned int u = __float_as_uint(f);
    return (unsigned short)((u + 0x7FFFu + ((u >> 16) & 1u)) >> 16);
}

// ---- Kernel 1: weight f32 [cin=512][p=512] -> bf16 ws[m=8][p=512][c=64] ----
__global__ __launch_bounds__(256) void wt_transpose_kernel(
    const float* __restrict__ weight, unsigned short* __restrict__ ws)
{
    __shared__ unsigned short stile[64 * 72];   // [p-local][c], stride 72
    const int m    = blockIdx.x >> 3;
    const int pblk = blockIdx.x & 7;
    const int t    = threadIdx.x;
    const int p    = t & 63;
    const int chi  = t >> 6;                    // 0..3
    #pragma unroll
    for (int r = 0; r < 16; ++r) {
        const int c = chi * 16 + r;
        const float v = weight[(size_t)(64 * m + c) * 512 + pblk * 64 + p]; // coalesced over p
        stile[p * 72 + c] = f32_to_bf16_rne(v);
    }
    __syncthreads();
    uint4* dst4 = (uint4*)(ws + (size_t)(m * 512 + pblk * 64) * 64);
    #pragma unroll
    for (int pass = 0; pass < 2; ++pass) {
        const int g = pass * 256 + t;           // granule 0..511 (64 rows x 8)
        const uint4 v = *(const uint4*)(stile + (g >> 3) * 72 + (g & 7) * 8);
        dst4[g] = v;                            // contiguous coalesced
    }
}

// ---- Kernel 2: main. One block per (b, m, w-pair). ----
__global__ __launch_bounds__(256, 4) void convdeidx_mfma_kernel(
    const int* __restrict__ ind_pos, const int* __restrict__ ind_neg,
    const float* __restrict__ val_pos, const float* __restrict__ val_neg,
    const unsigned short* __restrict__ ws, float* __restrict__ out)
{
    __shared__ unsigned short sX[2 * 64 * 72];    // 18 KB: [wl][h][c], stride 72

    const int bi  = blockIdx.x;                   // = ((b*8 + m)*32 + wg)
    const int wg  = bi & 31;
    const int m   = (bi >> 5) & 7;
    const int b   = bi >> 8;
    const int w0  = wg * 2;
    const int tid = threadIdx.x;
    const int wid = tid >> 6, lane = tid & 63;
    const int q   = lane >> 4, ln = lane & 15;    // quad, lane-in-16

    // ---- load pairs: threads 0..127 = (wl, h); one thread owns one X row ----
    int   ipos[4], ineg[4];
    float vpos[4], vneg[4];
    const int wl = (tid >> 6) & 1;
    const int h  = tid & 63;
    if (tid < 128) {
        #pragma unroll
        for (int k = 0; k < 4; ++k) {
            const size_t idx = ((((size_t)b * 4 + k) * 8 + m) * 64 + (w0 + wl)) * 64 + h;
            ipos[k] = ind_pos[idx]; vpos[k] = val_pos[idx];   // coalesced over h
            ineg[k] = ind_neg[idx]; vneg[k] = val_neg[idx];
        }
    }

    // ---- zero sX: 1152 uint4 ----
    {
        uint4* x4 = (uint4*)sX;
        const uint4 z = make_uint4(0u, 0u, 0u, 0u);
        #pragma unroll
        for (int r = 0; r < 4; ++r) x4[r * 256 + tid] = z;
        if (tid < 128) x4[1024 + tid] = z;
    }
    __syncthreads();

    // ---- densify: thread (wl,h) writes its 8 pairs in order -> last write wins
    if (tid < 128) {
        unsigned short* xrow = sX + (wl * 64 + h) * 72;
        #pragma unroll
        for (int k = 0; k < 4; ++k) xrow[ipos[k]] = f32_to_bf16_rne(vpos[k]);
        #pragma unroll
        for (int k = 0; k < 4; ++k) xrow[ineg[k]] = f32_to_bf16_rne(vneg[k]);
    }
    __syncthreads();

    // ---- main loop: barrier-free {A-frag from L2, B-frag from LDS, MFMA, store}
    const unsigned short* wsm = ws + (size_t)m * 512 * 64;
    f32x4* outv = (f32x4*)out;

    #pragma unroll
    for (int chunk = 0; chunk < 2; ++chunk) {
        // A fragments direct from global (L2-resident), fragment-contiguous:
        // row p = chunk*256 + wid*64 + mt*16 + ln, shorts [(kt*4+q)*8 ..+8)
        bf16x8 afr[2][4];
        #pragma unroll
        for (int kt = 0; kt < 2; ++kt)
            #pragma unroll
            for (int mt = 0; mt < 4; ++mt)
                afr[kt][mt] = *(const bf16x8*)(
                    wsm + ((size_t)(chunk * 256 + wid * 64 + mt * 16 + ln) << 6) + (kt * 4 + q) * 8);

        const int ocg0 = chunk * 16 + wid * 4;

        #pragma unroll
        for (int ww = 0; ww < 2; ++ww) {
            #pragma unroll
            for (int nh = 0; nh < 2; ++nh) {      // n-half: nt = nh*2 + nt2
                bf16x8 bfr[2][2];
                #pragma unroll
                for (int kt = 0; kt < 2; ++kt)
                    #pragma unroll
                    for (int nt2 = 0; nt2 < 2; ++nt2)
                        bfr[kt][nt2] = *(const bf16x8*)(
                            sX + (ww * 64 + (nh * 2 + nt2) * 16 + ln) * 72 + (kt * 4 + q) * 8);

                f32x4 acc[4][2];
                #pragma unroll
                for (int mt = 0; mt < 4; ++mt)
                    #pragma unroll
                    for (int nt2 = 0; nt2 < 2; ++nt2)
                        acc[mt][nt2] = (f32x4){0.f, 0.f, 0.f, 0.f};

                #pragma unroll
                for (int kt = 0; kt < 2; ++kt)
                    #pragma unroll
                    for (int mt = 0; mt < 4; ++mt)
                        #pragma unroll
                        for (int nt2 = 0; nt2 < 2; ++nt2)
                            acc[mt][nt2] = __builtin_amdgcn_mfma_f32_16x16x32_bf16(
                                afr[kt][mt], bfr[kt][nt2], acc[mt][nt2], 0, 0, 0);

                // stores: oc = chunk*16 + wid*4 + mt, oy = (w0+ww)*4 + q,
                //         col float4 = (nh*2+nt2)*16 + ln   -- PLAIN stores (A/B vs NT)
                #pragma unroll
                for (int mt = 0; mt < 4; ++mt) {
                    const size_t rowbase =
                        ((size_t)(b * 256 + m * 32 + ocg0 + mt) * 256 + ((w0 + ww) * 4 + q)) * 64;
                    #pragma unroll
                    for (int nt2 = 0; nt2 < 2; ++nt2)
                        outv[rowbase + (nh * 2 + nt2) * 16 + ln] = acc[mt][nt2];
                }
            }
        }
    }
}

extern "C" void kernel_launch(void* const* d_in, const int* in_sizes, int n_in,
                              void* d_out, int out_size, void* d_ws, size_t ws_size,
                              hipStream_t stream) {
    const int*   ind_pos = (const int*)  d_in[0];
    const int*   ind_neg = (const int*)  d_in[1];
    const float* val_pos = (const float*)d_in[2];
    const float* val_neg = (const float*)d_in[3];
    const float* weight  = (const float*)d_in[4];
    float*       y       = (float*)d_out;
    unsigned short* ws   = (unsigned short*)d_ws;   // needs 512 KB

    hipLaunchKernelGGL(wt_transpose_kernel, dim3(64), dim3(256), 0, stream, weight, ws);
    hipLaunchKernelGGL(convdeidx_mfma_kernel, dim3(1024), dim3(256), 0, stream,
                       ind_pos, ind_neg, val_pos, val_neg, ws, y);
}